// Round 3
// baseline (814.897 us; speedup 1.0000x reference)
//
#include <hip/hip_runtime.h>
#include <cstdint>
#include <cstddef>

// ---------------------------------------------------------------------------
// SwitchBack int8 MLP: x -> rowquant -> i8GEMM(+bias+gelu) -> rowquant ->
//                      i8GEMM(+bias) -> out
// N=8192 rows, D=2048, H=8192. All int8 matmul via mfma_i32_16x16x64_i8
// (exact integer arithmetic == reference fp32 matmul of int-valued floats).
//
// Workspace-adaptive: X2 f32 staging is processed in row-chunks sized from
// ws_size (97MB fixed + chunk*32KB). W2q aliases X1q (dead after GEMM1).
// ---------------------------------------------------------------------------

typedef int v4i __attribute__((ext_vector_type(4)));

#define AS1 __attribute__((address_space(1)))
#define AS3 __attribute__((address_space(3)))

__device__ __forceinline__ void gload_lds16(const void* g, void* l) {
    __builtin_amdgcn_global_load_lds((const AS1 void*)g, (AS3 void*)l, 16, 0, 0);
}

__device__ __forceinline__ float absmax4(float4 v, float cur) {
    return fmaxf(cur, fmaxf(fmaxf(fabsf(v.x), fabsf(v.y)),
                            fmaxf(fabsf(v.z), fabsf(v.w))));
}

__device__ __forceinline__ int quant1(float x, float inv) {
    int q = (int)rintf(x * inv);
    return min(127, max(-127, q));
}

__device__ __forceinline__ uint32_t quant4(float4 v, float inv) {
    uint32_t b0 = (uint32_t)(uint8_t)(int8_t)quant1(v.x, inv);
    uint32_t b1 = (uint32_t)(uint8_t)(int8_t)quant1(v.y, inv);
    uint32_t b2 = (uint32_t)(uint8_t)(int8_t)quant1(v.z, inv);
    uint32_t b3 = (uint32_t)(uint8_t)(int8_t)quant1(v.w, inv);
    return b0 | (b1 << 8) | (b2 << 16) | (b3 << 24);
}

// ---------------- global absmax of a big f32 array ----------------
__global__ __launch_bounds__(256) void wabs_kernel(
    const float* __restrict__ W, int n4, float* __restrict__ out)
{
    int tid = blockIdx.x * 256 + threadIdx.x;
    int stride = gridDim.x * 256;
    const float4* W4 = (const float4*)W;
    float amax = 0.0f;
    for (int i = tid; i < n4; i += stride) amax = absmax4(W4[i], amax);
    #pragma unroll
    for (int off = 32; off >= 1; off >>= 1)
        amax = fmaxf(amax, __shfl_xor(amax, off));
    __shared__ float red[4];
    if ((threadIdx.x & 63) == 0) red[threadIdx.x >> 6] = amax;
    __syncthreads();
    if (threadIdx.x == 0) {
        amax = fmaxf(fmaxf(red[0], red[1]), fmaxf(red[2], red[3]));
        atomicMax((int*)out, __float_as_int(amax));  // nonneg floats: int order ok
    }
}

// ---------------- quantize whole tensor with global scale ----------------
__global__ __launch_bounds__(256) void wquant_kernel(
    const float* __restrict__ W, int n4, const float* __restrict__ s,
    uint32_t* __restrict__ Wq)
{
    float inv = 127.0f / s[0];
    int tid = blockIdx.x * 256 + threadIdx.x;
    int stride = gridDim.x * 256;
    const float4* W4 = (const float4*)W;
    for (int i = tid; i < n4; i += stride) Wq[i] = quant4(W4[i], inv);
}

// ---------------- per-row absmax + quantize (one block per row) ----------------
// CNT = (cols/4)/256 float4 loads per thread; cols = CNT*1024
template<int CNT>
__global__ __launch_bounds__(256) void rowquant_kernel(
    const float* __restrict__ X, int8_t* __restrict__ Xq,
    float* __restrict__ rowAbs)
{
    const int row = blockIdx.x;
    const int t = threadIdx.x;
    const size_t cols = (size_t)CNT * 1024;
    const float4* Xr = (const float4*)(X + (size_t)row * cols);
    float4 vals[CNT];
    float amax = 0.0f;
    #pragma unroll
    for (int j = 0; j < CNT; j++) {
        vals[j] = Xr[j * 256 + t];
        amax = absmax4(vals[j], amax);
    }
    #pragma unroll
    for (int off = 32; off >= 1; off >>= 1)
        amax = fmaxf(amax, __shfl_xor(amax, off));
    __shared__ float red[4];
    if ((t & 63) == 0) red[t >> 6] = amax;
    __syncthreads();
    amax = fmaxf(fmaxf(red[0], red[1]), fmaxf(red[2], red[3]));
    if (t == 0) rowAbs[row] = amax;
    float inv = 127.0f / amax;
    uint32_t* out = (uint32_t*)(Xq + (size_t)row * cols);
    #pragma unroll
    for (int j = 0; j < CNT; j++) out[j * 256 + t] = quant4(vals[j], inv);
}

// ---------------- int8 GEMM, C[m,n] = sum_k A[m,k]*B[n,k] ----------------
// A: [M,K] i8 row-major, B: [Ncols,K] i8 row-major (both K-contiguous).
// 128x128 block tile, BK=128, 256 threads = 4 waves (2x2), each wave 64x64.
// Epilogue: dequant with rowScale[row]*wScale/127^2 + bias[col]; optional gelu.
template<int GELU>
__global__ __launch_bounds__(256) void gemm_i8_kernel(
    const int8_t* __restrict__ A, const int8_t* __restrict__ B,
    int K, int Ncols,
    const float* __restrict__ rowScale, const float* __restrict__ wScale,
    const float* __restrict__ bias, float* __restrict__ Cout)
{
    __shared__ alignas(16) int8_t As[128 * 128];
    __shared__ alignas(16) int8_t Bs[128 * 128];

    const int t = threadIdx.x;
    const int lane = t & 63;
    const int wid = t >> 6;
    const int brow = blockIdx.y * 128;
    const int bcol = blockIdx.x * 128;

    // staging: thread t covers LDS bytes [t*16, t*16+16) of each 4KB chunk
    // chunk i = rows [i*32, i*32+32); within chunk: row = t>>3, col16 = t&7
    const int sr = t >> 3;            // 0..31
    const int sc = (t & 7) * 16;      // 0..112
    const int8_t* Ag = A + (size_t)(brow + sr) * K + sc;
    const int8_t* Bg = B + (size_t)(bcol + sr) * K + sc;
    const size_t skip32 = (size_t)32 * K;

    v4i acc[4][4] = {};
    const int wr = (wid >> 1) * 64;
    const int wc = (wid & 1) * 64;
    const int llo = lane & 15;
    const int lhi = lane >> 4;

    const int nk = K >> 7;
    for (int kt = 0; kt < nk; ++kt) {
        __syncthreads();
        #pragma unroll
        for (int i = 0; i < 4; i++)
            gload_lds16(Ag + (size_t)i * skip32, &As[i * 4096 + t * 16]);
        #pragma unroll
        for (int i = 0; i < 4; i++)
            gload_lds16(Bg + (size_t)i * skip32, &Bs[i * 4096 + t * 16]);
        Ag += 128; Bg += 128;
        __syncthreads();  // compiler drains vmcnt before barrier

        #pragma unroll
        for (int ks = 0; ks < 2; ks++) {
            v4i a[4], b[4];
            #pragma unroll
            for (int m = 0; m < 4; m++)
                a[m] = *(const v4i*)&As[(wr + m * 16 + llo) * 128 + ks * 64 + lhi * 16];
            #pragma unroll
            for (int n = 0; n < 4; n++)
                b[n] = *(const v4i*)&Bs[(wc + n * 16 + llo) * 128 + ks * 64 + lhi * 16];
            #pragma unroll
            for (int m = 0; m < 4; m++)
                #pragma unroll
                for (int n = 0; n < 4; n++)
                    acc[m][n] = __builtin_amdgcn_mfma_i32_16x16x64_i8(
                        a[m], b[n], acc[m][n], 0, 0, 0);
        }
    }

    // epilogue: C/D layout col=lane&15, row=(lane>>4)*4+reg  [m89/m121 verified]
    const float ws = wScale[0] * (1.0f / (127.0f * 127.0f));
    #pragma unroll
    for (int m = 0; m < 4; m++) {
        #pragma unroll
        for (int r4 = 0; r4 < 4; r4++) {
            const int row = brow + wr + m * 16 + lhi * 4 + r4;
            const float s = rowScale[row] * ws;
            #pragma unroll
            for (int n = 0; n < 4; n++) {
                const int col = bcol + wc + n * 16 + llo;
                float v = (float)acc[m][n][r4] * s + bias[col];
                if (GELU) {
                    float u = v + 0.044715f * v * v * v;
                    v = 0.5f * v * (1.0f + tanhf(0.7978845608028654f * u));
                }
                Cout[(size_t)row * Ncols + col] = v;
            }
        }
    }
}

// ---------------------------------------------------------------------------
extern "C" void kernel_launch(void* const* d_in, const int* in_sizes, int n_in,
                              void* d_out, int out_size, void* d_ws, size_t ws_size,
                              hipStream_t stream)
{
    const float* x  = (const float*)d_in[0];   // [4,2048,2048] = [8192,2048]
    const float* W1 = (const float*)d_in[1];   // [8192,2048]
    const float* B1 = (const float*)d_in[2];   // [8192]
    const float* W2 = (const float*)d_in[3];   // [2048,8192]
    const float* B2 = (const float*)d_in[4];   // [2048]
    float* out = (float*)d_out;                // [8192,2048]

    const int N = 8192, D = 2048, H = 8192;
    const size_t MB = 1024 * 1024;

    // workspace layout (adaptive, ws_size-aware):
    //   [0, 64KB+): scales (sW1, sW2, sX1[N], sX2[N])
    //   1MB:   X1q [N*D]  16MB   (aliased by W2q after GEMM1 chunks finish)
    //   17MB:  W1q [H*D]  16MB
    //   33MB:  X2q [N*H]  64MB
    //   97MB:  X2f chunk staging, chunk*H*4 bytes
    char* ws = (char*)d_ws;
    float* sW1 = (float*)(ws + 0);
    float* sW2 = (float*)(ws + 4);
    float* sX1 = (float*)(ws + 256);                  // [N] floats
    float* sX2 = (float*)(ws + 256 + 32768);          // [N] floats
    size_t off = 1 * MB;
    int8_t* X1q = (int8_t*)(ws + off);
    int8_t* W2q = X1q;                                // alias: W2q created after X1q dead
    off += (size_t)N * D;                             // 16MB
    int8_t* W1q = (int8_t*)(ws + off); off += (size_t)H * D;   // 16MB
    int8_t* X2q = (int8_t*)(ws + off); off += (size_t)N * H;   // 64MB
    float*  X2f = (float*)(ws + off);                 // chunk * H * 4
    const size_t fixedBytes = off;

    // pick the largest chunk (multiple of 128 rows) whose f32 staging fits
    int chunk = N;
    if (ws_size < fixedBytes + (size_t)N * H * 4) {
        size_t avail = ws_size > fixedBytes ? ws_size - fixedBytes : 0;
        size_t c = avail / ((size_t)H * 4);
        c = (c / 128) * 128;
        if (c < 128) c = 128;          // last resort (needs ~97.5MB ws)
        if (c > (size_t)N) c = N;
        chunk = (int)c;
    }

    // zero the scale region (absmax atomics need 0 start; ws is poisoned 0xAA)
    hipMemsetAsync(d_ws, 0, 256 + 65536, stream);

    wabs_kernel<<<2048, 256, 0, stream>>>(W1, H * D / 4, sW1);
    wquant_kernel<<<4096, 256, 0, stream>>>(W1, H * D / 4, sW1, (uint32_t*)W1q);
    rowquant_kernel<2><<<N, 256, 0, stream>>>(x, X1q, sX1);

    for (int r0 = 0; r0 < N; r0 += chunk) {
        const int rows = min(chunk, N - r0);
        gemm_i8_kernel<1><<<dim3(H / 128, rows / 128), 256, 0, stream>>>(
            X1q + (size_t)r0 * D, W1q, D, H, sX1 + r0, sW1, B1, X2f);
        rowquant_kernel<8><<<rows, 256, 0, stream>>>(
            X2f, X2q + (size_t)r0 * H, sX2 + r0);
    }

    // W2 quantization after the chunk loop: X1q is dead, W2q aliases it
    wabs_kernel<<<2048, 256, 0, stream>>>(W2, D * H / 4, sW2);
    wquant_kernel<<<4096, 256, 0, stream>>>(W2, D * H / 4, sW2, (uint32_t*)W2q);

    gemm_i8_kernel<0><<<dim3(D / 128, N / 128), 256, 0, stream>>>(
        X2q, W2q, H, D, sX2, sW2, B2, out);
}

// Round 6
// 619.482 us; speedup vs baseline: 1.3154x; 1.3154x over previous
//
#include <hip/hip_runtime.h>
#include <cstdint>
#include <cstddef>

// ---------------------------------------------------------------------------
// SwitchBack int8 MLP: x -> rowquant -> i8GEMM(+bias+gelu) -> rowquant ->
//                      i8GEMM(+bias) -> out
// GEMM: 256x256 tile, BK=128, 8 waves, 8-phase schedule (T3+T4) with
// T2 source-side LDS swizzle, T5 setprio, T1 XCD swizzle.
// mfma_i32_16x16x64_i8 == exact integer arithmetic == reference fp32 matmul.
// ---------------------------------------------------------------------------

typedef int v4i __attribute__((ext_vector_type(4)));

#define AS1 __attribute__((address_space(1)))
#define AS3 __attribute__((address_space(3)))

#define WAIT_LGKM(N) asm volatile("s_waitcnt lgkmcnt(" #N ")" ::: "memory")
#define WAIT_VM(N)   asm volatile("s_waitcnt vmcnt(" #N ")" ::: "memory")
#define SBAR() __builtin_amdgcn_s_barrier()
#define SFENCE() __builtin_amdgcn_sched_barrier(0)

__device__ __forceinline__ void gload_lds16(const void* g, void* l) {
    __builtin_amdgcn_global_load_lds((const AS1 void*)g, (AS3 void*)l, 16, 0, 0);
}

__device__ __forceinline__ float absmax4(float4 v, float cur) {
    return fmaxf(cur, fmaxf(fmaxf(fabsf(v.x), fabsf(v.y)),
                            fmaxf(fabsf(v.z), fabsf(v.w))));
}

__device__ __forceinline__ int quant1(float x, float inv) {
    int q = (int)rintf(x * inv);
    return min(127, max(-127, q));
}

__device__ __forceinline__ uint32_t quant4(float4 v, float inv) {
    uint32_t b0 = (uint32_t)(uint8_t)(int8_t)quant1(v.x, inv);
    uint32_t b1 = (uint32_t)(uint8_t)(int8_t)quant1(v.y, inv);
    uint32_t b2 = (uint32_t)(uint8_t)(int8_t)quant1(v.z, inv);
    uint32_t b3 = (uint32_t)(uint8_t)(int8_t)quant1(v.w, inv);
    return b0 | (b1 << 8) | (b2 << 16) | (b3 << 24);
}

// ---------------- global absmax of a big f32 array ----------------
__global__ __launch_bounds__(256) void wabs_kernel(
    const float* __restrict__ W, int n4, float* __restrict__ out)
{
    int tid = blockIdx.x * 256 + threadIdx.x;
    int stride = gridDim.x * 256;
    const float4* W4 = (const float4*)W;
    float amax = 0.0f;
    for (int i = tid; i < n4; i += stride) amax = absmax4(W4[i], amax);
    #pragma unroll
    for (int off = 32; off >= 1; off >>= 1)
        amax = fmaxf(amax, __shfl_xor(amax, off));
    __shared__ float red[4];
    if ((threadIdx.x & 63) == 0) red[threadIdx.x >> 6] = amax;
    __syncthreads();
    if (threadIdx.x == 0) {
        amax = fmaxf(fmaxf(red[0], red[1]), fmaxf(red[2], red[3]));
        atomicMax((int*)out, __float_as_int(amax));  // nonneg floats: int order ok
    }
}

// ---------------- quantize whole tensor with global scale ----------------
__global__ __launch_bounds__(256) void wquant_kernel(
    const float* __restrict__ W, int n4, const float* __restrict__ s,
    uint32_t* __restrict__ Wq)
{
    float inv = 127.0f / s[0];
    int tid = blockIdx.x * 256 + threadIdx.x;
    int stride = gridDim.x * 256;
    const float4* W4 = (const float4*)W;
    for (int i = tid; i < n4; i += stride) Wq[i] = quant4(W4[i], inv);
}

// ---------------- per-row absmax + quantize (one block per row) ----------------
template<int CNT>
__global__ __launch_bounds__(256) void rowquant_kernel(
    const float* __restrict__ X, int8_t* __restrict__ Xq,
    float* __restrict__ rowAbs)
{
    const int row = blockIdx.x;
    const int t = threadIdx.x;
    const size_t cols = (size_t)CNT * 1024;
    const float4* Xr = (const float4*)(X + (size_t)row * cols);
    float4 vals[CNT];
    float amax = 0.0f;
    #pragma unroll
    for (int j = 0; j < CNT; j++) {
        vals[j] = Xr[j * 256 + t];
        amax = absmax4(vals[j], amax);
    }
    #pragma unroll
    for (int off = 32; off >= 1; off >>= 1)
        amax = fmaxf(amax, __shfl_xor(amax, off));
    __shared__ float red[4];
    if ((t & 63) == 0) red[t >> 6] = amax;
    __syncthreads();
    amax = fmaxf(fmaxf(red[0], red[1]), fmaxf(red[2], red[3]));
    if (t == 0) rowAbs[row] = amax;
    float inv = 127.0f / amax;
    uint32_t* out = (uint32_t*)(Xq + (size_t)row * cols);
    #pragma unroll
    for (int j = 0; j < CNT; j++) out[j * 256 + t] = quant4(vals[j], inv);
}

// ---------------- int8 GEMM, 256x256 tile, 8-phase (T1+T2+T3+T4+T5) --------
// A: [M,K] i8 row-major, B: [Ncols,K] i8 row-major. C[m,n] = sum A[m,k]B[n,k].
// 512 threads = 8 waves (2 wr x 4 wc), each wave owns 128x64 of C.
// LDS (dynamic 128KB): A [2buf][256][128], B [2buf][256][128].
// T2 swizzle: LDS row r, 16B-slot s holds global slot s^(r&7); gload_lds dest
// stays linear, the SOURCE address is pre-swizzled (rule #21, m173/m201).
// Phase schedule per K-tile T (buf=T&1), all reads drained by P2's lgkm(0):
//   P0: ds aA(m0-3,k0)+b0(4)=8;  stage A-h1(T+1); bar; lgkm0; 16 MFMA; bar
//   P1: ds aB(m4-7,k0)+b1+aC =12; stage B-h0(T+1); bar; lgkm8; 16 MFMA; bar
//   P2: ds aD(m4-7,k1)=4;        stage B-h1(T+1); bar; lgkm0; 16 MFMA; bar
//   P3:                          stage A-h0(T+2); 16 MFMA; vmcnt(2); bar
// vmcnt(2) leaves exactly the just-issued next-next-tile half in flight.
template<int GELU>
__global__ __launch_bounds__(512, 2) void gemm8_i8(
    const int8_t* __restrict__ A, const int8_t* __restrict__ B,
    int K, int Ncols, int nbx,
    const float* __restrict__ rowScale, const float* __restrict__ wScale,
    const float* __restrict__ bias, float* __restrict__ Cout)
{
    extern __shared__ int8_t lds[];
    int8_t* AsB = lds;            // [2][256][128]
    int8_t* BsB = lds + 65536;

    // T1: XCD-aware swizzle (all launches have gridDim.x % 8 == 0)
    const int nwg = gridDim.x;
    const int bid = blockIdx.x;
    const int wg = (bid & 7) * (nwg >> 3) + (bid >> 3);
    const int bx = wg % nbx;
    const int by = wg / nbx;
    const int brow = by * 256;
    const int bcol = bx * 256;

    const int t = threadIdx.x;
    const int lane = t & 63;
    const int w = t >> 6;          // wave 0..7
    const int wr = w >> 2;         // 0..1
    const int wc = w & 3;          // 0..3
    const int llo = lane & 15;
    const int lhi = lane >> 4;

    const int8_t* gA = A + (size_t)brow * K;
    const int8_t* gB = B + (size_t)bcol * K;

    // staging constants: thread t, load j covers LDS bytes j*8192 + t*16
    // -> LDS row (j*64 + t>>3), slot t&7; source slot pre-swizzled.
    const int rq = t >> 3;                          // 0..63
    const int sl = (t & 7) ^ (rq & 7);              // swizzled source slot
    const size_t srcOffBase = (size_t)rq * K + (size_t)sl * 16;
    const int ldsDst = t * 16;

    // reader offsets (swizzled slot = (kslot ^ (row&7)); row&7 == llo&7)
    const int aRow = (wr * 128 + llo) * 128;
    const int bRow = (wc * 64 + llo) * 128;
    const int s0 = ((lhi) ^ (llo & 7)) * 16;        // kstep0 slot byte
    const int s1 = ((4 + lhi) ^ (llo & 7)) * 16;    // kstep1 slot byte

    const int NT = K >> 7;

    v4i acc[8][4] = {};

    // stage one 128-row half: halfId 0=A rows0-127,1=A rows128-255,2=B0,3=B1
    auto stage = [&](int halfId, int par, int srcTile) {
        const int8_t* g = (halfId >= 2) ? gB : gA;
        int8_t* ldsOp = (halfId >= 2) ? BsB : AsB;
        const int hh = halfId & 1;
        const size_t gb = (size_t)(hh * 128) * (size_t)K
                        + (size_t)srcTile * 128 + srcOffBase;
        int8_t* d = ldsOp + par * 32768 + hh * 16384 + ldsDst;
        gload_lds16(g + gb, d);
        gload_lds16(g + gb + (size_t)64 * K, d + 8192);
    };

    // prologue: tile0 all 4 halves + tile1 A-h0 (10 loads; keep last 2 in flight)
    {
        const int t1 = NT > 1 ? 1 : 0;
        stage(0, 0, 0); stage(1, 0, 0); stage(2, 0, 0); stage(3, 0, 0);
        stage(0, 1, t1);
    }
    WAIT_VM(2);
    SFENCE();
    SBAR();

    #define MFMA16(AV, BV, MOFF)                                            \
        __builtin_amdgcn_s_setprio(1);                                      \
        _Pragma("unroll")                                                   \
        for (int m = 0; m < 4; m++)                                         \
            _Pragma("unroll")                                               \
            for (int n = 0; n < 4; n++)                                     \
                acc[MOFF + m][n] = __builtin_amdgcn_mfma_i32_16x16x64_i8(   \
                    AV[m], BV[n], acc[MOFF + m][n], 0, 0, 0);               \
        __builtin_amdgcn_s_setprio(0);

    for (int T = 0; T < NT; ++T) {
        const int buf = T & 1;
        const int8_t* Ab = AsB + buf * 32768;
        const int8_t* Bb = BsB + buf * 32768;
        const int tn  = (T + 1 < NT) ? T + 1 : T;   // clamped sources keep
        const int tn2 = (T + 2 < NT) ? T + 2 : T;   // vmcnt counts uniform
        const int parN = (T + 1) & 1;

        v4i aA[4], aB_[4], aC[4], aD[4], b0[4], b1[4];

        // ---- P0 ----
        #pragma unroll
        for (int m = 0; m < 4; m++) aA[m] = *(const v4i*)(Ab + aRow + m * 2048 + s0);
        #pragma unroll
        for (int n = 0; n < 4; n++) b0[n] = *(const v4i*)(Bb + bRow + n * 2048 + s0);
        stage(1, parN, tn);
        SBAR();
        WAIT_LGKM(0);
        SFENCE();
        MFMA16(aA, b0, 0)
        SBAR();

        // ---- P1 ---- (12 reads: aB_ first so lgkm(8) drains it)
        #pragma unroll
        for (int m = 0; m < 4; m++) aB_[m] = *(const v4i*)(Ab + aRow + 8192 + m * 2048 + s0);
        #pragma unroll
        for (int n = 0; n < 4; n++) b1[n] = *(const v4i*)(Bb + bRow + n * 2048 + s1);
        #pragma unroll
        for (int m = 0; m < 4; m++) aC[m] = *(const v4i*)(Ab + aRow + m * 2048 + s1);
        stage(2, parN, tn);
        SBAR();
        WAIT_LGKM(8);
        SFENCE();
        MFMA16(aB_, b0, 4)
        SBAR();

        // ---- P2 ---- (last reads of this buffer; lgkm(0) drains ALL tile reads)
        #pragma unroll
        for (int m = 0; m < 4; m++) aD[m] = *(const v4i*)(Ab + aRow + 8192 + m * 2048 + s1);
        stage(3, parN, tn);
        SBAR();
        WAIT_LGKM(0);
        SFENCE();
        MFMA16(aC, b1, 0)
        SBAR();

        // ---- P3 ---- (safe to overwrite buf: all reads drained at P2)
        stage(0, buf, tn2);
        MFMA16(aD, b1, 4)
        WAIT_VM(2);
        SFENCE();
        SBAR();
    }
    #undef MFMA16

    // epilogue: C/D layout col=lane&15, row=(lane>>4)*4+reg
    const float wsc = wScale[0] * (1.0f / (127.0f * 127.0f));
    #pragma unroll
    for (int m = 0; m < 8; m++) {
        #pragma unroll
        for (int r4 = 0; r4 < 4; r4++) {
            const int row = brow + wr * 128 + m * 16 + lhi * 4 + r4;
            const float s = rowScale[row] * wsc;
            #pragma unroll
            for (int n = 0; n < 4; n++) {
                const int col = bcol + wc * 64 + n * 16 + llo;
                float v = (float)acc[m][n][r4] * s + bias[col];
                if (GELU) {
                    float u = v + 0.044715f * v * v * v;
                    v = v / (1.0f + __expf(-1.5957691216057308f * u));
                }
                Cout[(size_t)row * Ncols + col] = v;
            }
        }
    }
}

// ---------------------------------------------------------------------------
extern "C" void kernel_launch(void* const* d_in, const int* in_sizes, int n_in,
                              void* d_out, int out_size, void* d_ws, size_t ws_size,
                              hipStream_t stream)
{
    const float* x  = (const float*)d_in[0];   // [8192,2048]
    const float* W1 = (const float*)d_in[1];   // [8192,2048]
    const float* B1 = (const float*)d_in[2];   // [8192]
    const float* W2 = (const float*)d_in[3];   // [2048,8192]
    const float* B2 = (const float*)d_in[4];   // [2048]
    float* out = (float*)d_out;                // [8192,2048]

    const int N = 8192, D = 2048, H = 8192;
    const size_t MB = 1024 * 1024;

    // 128KB dynamic LDS opt-in (host-side attribute set; not a stream op)
    hipFuncSetAttribute((const void*)gemm8_i8<1>,
                        hipFuncAttributeMaxDynamicSharedMemorySize, 131072);
    hipFuncSetAttribute((const void*)gemm8_i8<0>,
                        hipFuncAttributeMaxDynamicSharedMemorySize, 131072);

    // workspace layout (adaptive):
    //   0..64KB+: scales; 1MB: X1q 16MB (aliased by W2q later); 17MB: W1q 16MB;
    //   33MB: X2q 64MB; 97MB: X2f chunk staging (chunk*H*4 bytes)
    char* ws = (char*)d_ws;
    float* sW1 = (float*)(ws + 0);
    float* sW2 = (float*)(ws + 4);
    float* sX1 = (float*)(ws + 256);
    float* sX2 = (float*)(ws + 256 + 32768);
    size_t off = 1 * MB;
    int8_t* X1q = (int8_t*)(ws + off);
    int8_t* W2q = X1q;                 // alias: W2q written after X1q is dead
    off += (size_t)N * D;
    int8_t* W1q = (int8_t*)(ws + off); off += (size_t)H * D;
    int8_t* X2q = (int8_t*)(ws + off); off += (size_t)N * H;
    float*  X2f = (float*)(ws + off);
    const size_t fixedBytes = off;

    // largest chunk (multiple of 256 rows) whose f32 staging fits
    int chunk = N;
    if (ws_size < fixedBytes + (size_t)N * H * 4) {
        size_t avail = ws_size > fixedBytes ? ws_size - fixedBytes : 0;
        size_t c = avail / ((size_t)H * 4);
        c = (c / 256) * 256;
        if (c < 256) c = 256;
        if (c > (size_t)N) c = N;
        chunk = (int)c;
    }

    hipMemsetAsync(d_ws, 0, 256 + 65536, stream);

    wabs_kernel<<<2048, 256, 0, stream>>>(W1, H * D / 4, sW1);
    wquant_kernel<<<4096, 256, 0, stream>>>(W1, H * D / 4, sW1, (uint32_t*)W1q);
    rowquant_kernel<2><<<N, 256, 0, stream>>>(x, X1q, sX1);

    for (int r0 = 0; r0 < N; r0 += chunk) {
        const int rows = min(chunk, N - r0);
        gemm8_i8<1><<<(H / 256) * (rows / 256), 512, 131072, stream>>>(
            X1q + (size_t)r0 * D, W1q, D, H, H / 256,
            sX1 + r0, sW1, B1, X2f);
        rowquant_kernel<8><<<rows, 256, 0, stream>>>(
            X2f, X2q + (size_t)r0 * H, sX2 + r0);
    }

    wabs_kernel<<<2048, 256, 0, stream>>>(W2, D * H / 4, sW2);
    wquant_kernel<<<4096, 256, 0, stream>>>(W2, D * H / 4, sW2, (uint32_t*)W2q);

    gemm8_i8<0><<<(D / 256) * (N / 256), 512, 131072, stream>>>(
        X2q, W2q, H, D, D / 256, sX2, sW2, B2, out);
}